// Round 7
// baseline (409.278 us; speedup 1.0000x reference)
//
#include <hip/hip_runtime.h>

#define N_NODES 100000
#define N_EDGES 800000
#define NF 81
#define NB 22
#define OC 64
#define SCAN_CHUNK 1024
#define SCAN_BLOCKS ((N_NODES + SCAN_CHUNK - 1) / SCAN_CHUNK)   // 98
#define AS 84                       // LDS A row stride (81 + 3 pad)
#define REC_DW 32                   // 128B record stride: dw0=inv dw1=tid dw2..23=bond

typedef __attribute__((ext_vector_type(2))) float v2f;

__device__ inline unsigned pk2bf16(float a, float b) {
    const unsigned ua = (__float_as_uint(a) + 0x8000u) >> 16;
    const unsigned ub = (__float_as_uint(b) + 0x8000u) & 0xffff0000u;
    return ua | ub;
}
__device__ inline float bf2f(unsigned u) { return __uint_as_float(u << 16); }

// ---------------------------------------------------------------------------
// Fused node GEMM: out(f32) = feat@w_s ; pbh(bf16) = feat@w_n[:81] ; xyz.
// 64 nodes x 128 ch per block; A-tile ONLY in LDS (21.5 KB, row-major
// stride 84: staging writes bank-step 1 = conflict-free, reads 2-way = free).
// W read from global (L1/L2-hot, same 41 KB for all blocks) with 2-stage
// float4 prefetch. Thread (tx,ty): 4 nodes x 8 channels; ty<8 -> w_s/out,
// ty>=8 -> w_n/pbh.  R6 failure fixed: LDS 64KB->21.5KB (2->5 blocks/CU),
// 703K bank conflicts -> 0.
__global__ __launch_bounds__(256) void k_node4(
    const float* __restrict__ feat, const float* __restrict__ w_s,
    const float* __restrict__ w_n, float* __restrict__ out,
    unsigned short* __restrict__ pbh, float4* __restrict__ xyz)
{
    __shared__ float shA[64 * AS];                // 21,504 B
    const int t  = threadIdx.x;
    const int n0 = blockIdx.x * 64;

    const long gbase = (long)n0 * NF;
    const long gtot  = (long)N_NODES * NF;
    for (int f = t; f < 64 * NF; f += 256) {
        const int n = f / NF;
        const int k = f - n * NF;
        shA[n * AS + k] = (gbase + f < gtot) ? feat[gbase + f] : 0.f;
    }
    __syncthreads();

    if (t < 64 && n0 + t < N_NODES)
        xyz[n0 + t] = make_float4(shA[t * AS + 0], shA[t * AS + 1],
                                  shA[t * AS + 2], 0.f);

    const int tx = t & 15;                        // node group
    const int ty = t >> 4;                        // channel-8 group
    const float* W = ((ty < 8) ? w_s : w_n) + (ty & 7) * 8;

    float acc[4][8];
#pragma unroll
    for (int i = 0; i < 4; ++i)
#pragma unroll
        for (int j = 0; j < 8; ++j) acc[i][j] = 0.f;

    const float* a0p = shA + (tx * 4 + 0) * AS;
    const float* a1p = shA + (tx * 4 + 1) * AS;
    const float* a2p = shA + (tx * 4 + 2) * AS;
    const float* a3p = shA + (tx * 4 + 3) * AS;

    float4 wc0 = *(const float4*)(W);             // k = 0
    float4 wc1 = *(const float4*)(W + 4);
#pragma unroll 3
    for (int k = 0; k < NF; ++k) {
        const int kn = (k + 1 < NF) ? k + 1 : k;  // prefetch next k
        const float4 wn0 = *(const float4*)(W + kn * OC);
        const float4 wn1 = *(const float4*)(W + kn * OC + 4);
        const float a0 = a0p[k], a1 = a1p[k], a2 = a2p[k], a3 = a3p[k];
        const float av[4] = {a0, a1, a2, a3};
        const float wv[8] = {wc0.x, wc0.y, wc0.z, wc0.w,
                             wc1.x, wc1.y, wc1.z, wc1.w};
#pragma unroll
        for (int i = 0; i < 4; ++i)
#pragma unroll
            for (int j = 0; j < 8; ++j)
                acc[i][j] += av[i] * wv[j];
        wc0 = wn0; wc1 = wn1;
    }

    const int cb = (ty & 7) * 8;
#pragma unroll
    for (int i = 0; i < 4; ++i) {
        const int node = n0 + tx * 4 + i;
        if (node >= N_NODES) continue;
        if (ty < 8) {
            float* p = out + (long)node * OC + cb;
            *(float4*)(p)     = make_float4(acc[i][0], acc[i][1], acc[i][2], acc[i][3]);
            *(float4*)(p + 4) = make_float4(acc[i][4], acc[i][5], acc[i][6], acc[i][7]);
        } else {
            unsigned* p = (unsigned*)(pbh + (long)node * OC + cb);
            *(uint4*)p = make_uint4(pk2bf16(acc[i][0], acc[i][1]),
                                    pk2bf16(acc[i][2], acc[i][3]),
                                    pk2bf16(acc[i][4], acc[i][5]),
                                    pk2bf16(acc[i][6], acc[i][7]));
        }
    }
}

// ---------------------------------------------------------------------------
__global__ void k_hist(const int* __restrict__ src, int* __restrict__ cnt) {
    const int e = blockIdx.x * blockDim.x + threadIdx.x;
    if (e < N_EDGES) atomicAdd(&cnt[src[e]], 1);
}

__global__ __launch_bounds__(256) void k_scan_blk(
    const int* __restrict__ cnt, int* __restrict__ row, int* __restrict__ bsum)
{
    __shared__ int sh[256];
    const int t = threadIdx.x;
    const int base = blockIdx.x * SCAN_CHUNK + t * 4;
    int c0 = 0, c1 = 0, c2 = 0, c3 = 0;
    if (base + 3 < N_NODES) {
        const int4 c = *(const int4*)(cnt + base);
        c0 = c.x; c1 = c.y; c2 = c.z; c3 = c.w;
    } else {
        if (base + 0 < N_NODES) c0 = cnt[base + 0];
        if (base + 1 < N_NODES) c1 = cnt[base + 1];
        if (base + 2 < N_NODES) c2 = cnt[base + 2];
    }
    const int s = c0 + c1 + c2 + c3;
    sh[t] = s;
    __syncthreads();
    for (int off = 1; off < 256; off <<= 1) {
        int v = sh[t];
        int a = (t >= off) ? sh[t - off] : 0;
        __syncthreads();
        sh[t] = v + a;
        __syncthreads();
    }
    const int excl = sh[t] - s;
    if (t == 255) bsum[blockIdx.x] = sh[255];
    if (base + 3 < N_NODES) {
        int4 r;
        r.x = excl; r.y = excl + c0; r.z = excl + c0 + c1; r.w = excl + c0 + c1 + c2;
        *(int4*)(row + base) = r;
    } else {
        int e = excl;
        if (base + 0 < N_NODES) { row[base + 0] = e; e += c0; }
        if (base + 1 < N_NODES) { row[base + 1] = e; e += c1; }
        if (base + 2 < N_NODES) { row[base + 2] = e; }
    }
}

__global__ void k_scan_top(int* __restrict__ bsum, int* __restrict__ row) {
    __shared__ int sh[128];
    const int t = threadIdx.x;
    const int v = (t < SCAN_BLOCKS) ? bsum[t] : 0;
    sh[t] = v;
    __syncthreads();
    for (int off = 1; off < 128; off <<= 1) {
        int x = sh[t];
        int a = (t >= off) ? sh[t - off] : 0;
        __syncthreads();
        sh[t] = x + a;
        __syncthreads();
    }
    if (t < SCAN_BLOCKS) bsum[t] = sh[t] - v;
    if (t == 127) row[N_NODES] = sh[127];
}

__global__ __launch_bounds__(256) void k_scan_add(
    int* __restrict__ row, int* __restrict__ cursor, const int* __restrict__ bsum)
{
    const int off = bsum[blockIdx.x];
    const int base = blockIdx.x * SCAN_CHUNK + threadIdx.x * 4;
    if (base + 3 < N_NODES) {
        int4 r = *(const int4*)(row + base);
        r.x += off; r.y += off; r.z += off; r.w += off;
        *(int4*)(row + base) = r;
        *(int4*)(cursor + base) = r;
    } else {
#pragma unroll
        for (int k = 0; k < 4; ++k)
            if (base + k < N_NODES) {
                const int v = row[base + k] + off;
                row[base + k] = v;
                cursor[base + k] = v;
            }
    }
}

// ---------------------------------------------------------------------------
// Scatter a 96B record into the 128B src-sorted slot:
//   dw0 = inv (f32), dw1 = dst id, dw2..23 = bond row (f32).
__global__ void k_prep(const int* __restrict__ src, const int* __restrict__ dst,
                       const float* __restrict__ bond, const float4* __restrict__ xyz,
                       int* __restrict__ cursor, unsigned* __restrict__ rec)
{
    const int e = blockIdx.x * blockDim.x + threadIdx.x;
    if (e >= N_EDGES) return;
    const int s = src[e];
    const int d = dst[e];
    const float4 a = xyz[s], b = xyz[d];
    const float dx = a.x - b.x, dy = a.y - b.y, dz = a.z - b.z;
    const float d2 = dx * dx + dy * dy + dz * dz;
    const float inv = (d2 > 0.f) ? __builtin_amdgcn_rcpf(d2) : 1.0e4f;

    float bv[NB];
    const float2* bp = (const float2*)(bond + (long)e * NB);
#pragma unroll
    for (int j = 0; j < NB / 2; ++j) {
        const float2 v = bp[j];
        bv[2 * j] = v.x; bv[2 * j + 1] = v.y;
    }

    const int pos = atomicAdd(&cursor[s], 1);
    unsigned* r = rec + (size_t)pos * REC_DW;
    *(uint4*)(r + 0)  = make_uint4(__float_as_uint(inv), (unsigned)d,
                                   __float_as_uint(bv[0]), __float_as_uint(bv[1]));
#pragma unroll
    for (int q = 0; q < 5; ++q)
        *(uint4*)(r + 4 + q * 4) = make_uint4(
            __float_as_uint(bv[2 + 4 * q + 0]), __float_as_uint(bv[2 + 4 * q + 1]),
            __float_as_uint(bv[2 + 4 * q + 2]), __float_as_uint(bv[2 + 4 * q + 3]));
}

// ---------------------------------------------------------------------------
// Gather: wave per node, lane = channel, no atomics.
// Per edge: 24-dword uniform record (batched s_loads) + 1 bf16 pb gather
// + ~15 VALU ops (11 float2 bond-sum adds -> v_pk_add_f32, 2 fmacs).
// Bond projection (22 fmacs with w_nb) applied ONCE per node at the end:
//   sum_e [inv*(pa+pbt) + bond_e@w_nb] = pa*sinv + sum inv*pbt + (sum bond_e)@w_nb
__global__ __launch_bounds__(256) void k_gather(
    const int* __restrict__ row, const unsigned* __restrict__ rec,
    const float* __restrict__ w_n, const unsigned short* __restrict__ pbh,
    const float4* __restrict__ xyz, float* __restrict__ out)
{
    const int lane = threadIdx.x & 63;
    const int wid  = (int)((blockIdx.x * blockDim.x + threadIdx.x) >> 6);
    if (wid >= N_NODES) return;
    const int n = __builtin_amdgcn_readfirstlane(wid);

    float wnb[NB];
#pragma unroll
    for (int j = 0; j < NB; ++j) wnb[j] = w_n[(NF + j) * OC + lane];
    const float w0 = w_n[0 * OC + lane];
    const float w1 = w_n[1 * OC + lane];
    const float w2 = w_n[2 * OC + lane];

    const int rs = row[n], re = row[n + 1];
    const float4 xs = xyz[n];
    const float pa = bf2f(pbh[(long)n * OC + lane])
                   - (xs.x * w0 + xs.y * w1 + xs.z * w2);

    float acc = 0.f, sinv = 0.f;
    v2f bsum[11];
#pragma unroll
    for (int j = 0; j < 11; ++j) bsum[j] = (v2f){0.f, 0.f};

    int i = rs;
    for (; i + 2 <= re; i += 2) {
        const unsigned* rA = rec + (size_t)i * REC_DW;
        const unsigned* rB = rA + REC_DW;
        unsigned a[24], b[24];
#pragma unroll
        for (int j = 0; j < 24; ++j) a[j] = rA[j];    // uniform -> s_load batch
#pragma unroll
        for (int j = 0; j < 24; ++j) b[j] = rB[j];
        const float invA = __uint_as_float(a[0]);
        const float invB = __uint_as_float(b[0]);
        const int   tA   = (int)a[1];
        const int   tB   = (int)b[1];
        const float pbtA = bf2f(pbh[(long)tA * OC + lane]);
        const float pbtB = bf2f(pbh[(long)tB * OC + lane]);
        acc  += invA * pbtA + invB * pbtB;
        sinv += invA + invB;
#pragma unroll
        for (int j = 0; j < 11; ++j) {
            const v2f va = {__uint_as_float(a[2 + 2 * j]), __uint_as_float(a[3 + 2 * j])};
            const v2f vb = {__uint_as_float(b[2 + 2 * j]), __uint_as_float(b[3 + 2 * j])};
            bsum[j] += va + vb;                       // v_pk_add_f32
        }
    }
    if (i < re) {
        const unsigned* rA = rec + (size_t)i * REC_DW;
        unsigned a[24];
#pragma unroll
        for (int j = 0; j < 24; ++j) a[j] = rA[j];
        const float invA = __uint_as_float(a[0]);
        const int   tA   = (int)a[1];
        acc  += invA * bf2f(pbh[(long)tA * OC + lane]);
        sinv += invA;
#pragma unroll
        for (int j = 0; j < 11; ++j) {
            const v2f va = {__uint_as_float(a[2 + 2 * j]), __uint_as_float(a[3 + 2 * j])};
            bsum[j] += va;
        }
    }

    float bacc = 0.f;
#pragma unroll
    for (int j = 0; j < 11; ++j)
        bacc += bsum[j].x * wnb[2 * j] + bsum[j].y * wnb[2 * j + 1];

    out[(long)n * OC + lane] += acc + pa * sinv + bacc;
}

// ---------------------------------------------------------------------------
extern "C" void kernel_launch(void* const* d_in, const int* in_sizes, int n_in,
                              void* d_out, int out_size, void* d_ws, size_t ws_size,
                              hipStream_t stream) {
    const float* feat = (const float*)d_in[0];
    const float* bond = (const float*)d_in[1];
    const float* w_s  = (const float*)d_in[2];
    const float* w_n  = (const float*)d_in[3];
    const int*   src  = (const int*)d_in[4];
    const int*   dstv = (const int*)d_in[5];
    float* out = (float*)d_out;

    // workspace layout (aligned), ~118 MB total
    char* base = (char*)d_ws;
    float4*         xyz    = (float4*)        (base);               //  1,600,000
    unsigned short* pbh    = (unsigned short*)(base + 1600000);     // 12,800,000
    int*            row    = (int*)           (base + 14400000);    //    400,004
    int*            cnt    = (int*)           (base + 14800016);    //    400,000
    int*            cursor = (int*)           (base + 15200016);    //    400,000
    int*            bsum   = (int*)           (base + 15600016);    //        512
    unsigned*       rec    = (unsigned*)      (base + 15600640);    // 102,400,000

    hipMemsetAsync(cnt, 0, N_NODES * sizeof(int), stream);

    k_node4   <<<(N_NODES + 63) / 64, 256, 0, stream>>>(feat, w_s, w_n, out, pbh, xyz);
    k_hist    <<<(N_EDGES + 255) / 256, 256, 0, stream>>>(src, cnt);
    k_scan_blk<<<SCAN_BLOCKS, 256, 0, stream>>>(cnt, row, bsum);
    k_scan_top<<<1, 128, 0, stream>>>(bsum, row);
    k_scan_add<<<SCAN_BLOCKS, 256, 0, stream>>>(row, cursor, bsum);
    k_prep    <<<(N_EDGES + 255) / 256, 256, 0, stream>>>(src, dstv, bond, xyz,
                                                          cursor, rec);
    k_gather  <<<(N_NODES * 64 + 255) / 256, 256, 0, stream>>>(row, rec, w_n, pbh,
                                                               xyz, out);
}